// Round 4
// baseline (246.960 us; speedup 1.0000x reference)
//
#include <hip/hip_runtime.h>

// Problem constants (fixed by setup_inputs): B=8, S=4096, H=1024
constexpr int Bn  = 8;
constexpr int Sn  = 4096;
constexpr int Nn  = Bn * Sn;          // 32768 labels
constexpr int Hn  = 1024;

constexpr int TPB = 256;              // block size (copy blocks and scan block)
constexpr int NW  = TPB / 64;         // 4 waves in scan block
constexpr int G4    = Nn / 4;         // 8192 int4 label groups
constexpr int ITERS = G4 / TPB;       // 32 coalesced iterations over labels

constexpr size_t FEAT_ELEMS = (size_t)Nn * Hn;        // 33,554,432 floats
constexpr size_t FEAT_VEC4  = FEAT_ELEMS / 4;         // 8,388,608 float4
constexpr int    COPY_BLOCKS = 2048;                  // Guideline 11: cap ~2048
constexpr int    VEC_PER_T   = (int)(FEAT_VEC4 / ((size_t)COPY_BLOCKS * TPB)); // 16
constexpr int    BATCH       = 8;                     // float4 in flight per batch
constexpr int    NBATCH      = VEC_PER_T / BATCH;     // 2

typedef float v4f __attribute__((ext_vector_type(4)));

// Fused kernel.
//   block 0:                 coalesced single-block scan producing segment ids.
//   blocks [1, COPY_BLOCKS]: each copies one CONTIGUOUS 64 KB chunk as two
//                            8-deep batches.
// ROUND-4 CHANGE — split cache policy by stream (counter-driven, r3 evidence):
//   * loads  = PLAIN:  input is 134 MB < 256 MB L3 -> allow L3 allocation/hits.
//     (r3 FETCH_SIZE=67MB proved half the reads already hit L3 even when
//     thrashed; preserving residency pushes this further.)
//   * stores = NONTEMPORAL: write-once stream must NOT allocate in L2/L3 —
//     r3's plain stores (134MB write + 134MB read > 256MB L3) thrashed the
//     input out of L3. This was the r3 regression mechanism.
//   * 2048 persistent-ish blocks x 16 float4/thread instead of 4096 one-shot
//     blocks x 8 (block launch/drain amortization, Guideline 11).
__global__ __launch_bounds__(TPB) void fused_kernel(const float* __restrict__ seq,
                                                    const int* __restrict__ labels,
                                                    float* __restrict__ out) {
    if (blockIdx.x > 0) {
        const v4f* __restrict__ src = reinterpret_cast<const v4f*>(seq);
        v4f* __restrict__ dst       = reinterpret_cast<v4f*>(out);
        // block-contiguous 64 KB chunk: [cb*4096, (cb+1)*4096) float4
        const size_t base0 = (size_t)(blockIdx.x - 1) * (TPB * VEC_PER_T) + threadIdx.x;
#pragma unroll
        for (int k = 0; k < NBATCH; ++k) {
            const size_t base = base0 + (size_t)k * (TPB * BATCH);
            v4f r[BATCH];
#pragma unroll
            for (int i = 0; i < BATCH; ++i)
                r[i] = src[base + (size_t)i * TPB];           // plain: may hit/allocate L3
#pragma unroll
            for (int i = 0; i < BATCH; ++i)
                __builtin_nontemporal_store(r[i], &dst[base + (size_t)i * TPB]); // NT: no L3 pollution
        }
        return;
    }

    // ---- scan part (block 0): all 32768 segment ids, fully coalesced ----
    // range r (r = 0..255) = labels [r*128, r*128+128) = int4 groups [r*32, r*32+32)
    __shared__ int range_pre[TPB];     // per-range zero counts -> exclusive offsets
    __shared__ int wave_sums[NW];
    __shared__ int extra_off_sh[Bn];

    const int tid  = threadIdx.x;
    const int lane = tid & 63;
    const int hl   = lane & 31;        // lane within 32-lane half-wave
    const int wave = tid >> 6;

    const int4* __restrict__ lab4 = reinterpret_cast<const int4*>(labels);
    v4f* __restrict__ seg4 = reinterpret_cast<v4f*>(out + FEAT_ELEMS);

    // Pass 1: coalesced zero-counting. Each iteration the block reads 256
    // consecutive int4 (4 KB contiguous); each 32-lane half-wave covers
    // exactly one range (32 consecutive int4 = 128 labels).
#pragma unroll 4
    for (int i = 0; i < ITERS; ++i) {
        const int g = i * TPB + tid;
        int4 v = lab4[g];
        int c = (v.x == 0) + (v.y == 0) + (v.z == 0) + (v.w == 0);
#pragma unroll
        for (int k = 1; k < 32; k <<= 1) c += __shfl_xor(c, k, 32);
        if (hl == 0) range_pre[g >> 5] = c;   // g>>5 = range id, unique writer
    }

    // Tiny serial job: exclusive scan of the 8 per-example "extra" bits
    if (tid == 0) {
        int acc = 0;
#pragma unroll
        for (int b = 0; b < Bn; ++b) {
            extra_off_sh[b] = acc;
            acc += (labels[b * Sn + Sn - 1] == 1);
        }
    }
    __syncthreads();

    // Thread-level scan of the 256 range sums (wave scan + cross-wave fixup)
    const int s = range_pre[tid];
    int incl = s;
#pragma unroll
    for (int off = 1; off < 64; off <<= 1) {
        int u = __shfl_up(incl, off, 64);
        if (lane >= off) incl += u;
    }
    if (lane == 63) wave_sums[wave] = incl;
    __syncthreads();

    if (wave == 0) {
        int v = (lane < NW) ? wave_sums[lane] : 0;
#pragma unroll
        for (int off = 1; off < NW; off <<= 1) {
            int u = __shfl_up(v, off, 64);
            if (lane >= off) v += u;
        }
        if (lane < NW) wave_sums[lane] = v;
    }
    __syncthreads();

    // exclusive zero-count before range tid; in-place (own slot only)
    range_pre[tid] = (wave ? wave_sums[wave - 1] : 0) + (incl - s);
    __syncthreads();

    // Pass 2: coalesced emit. Re-read labels (L2-hot), 32-lane shfl prefix
    // gives the within-range exclusive count; emit coalesced float4 stores.
    // Segment ids (max ~16.4k) are exact in fp32.
#pragma unroll 4
    for (int i = 0; i < ITERS; ++i) {
        const int g = i * TPB + tid;
        int4 v = lab4[g];
        const int f0 = (v.x == 0), f1 = (v.y == 0), f2 = (v.z == 0), f3 = (v.w == 0);
        const int c = f0 + f1 + f2 + f3;
        int pc = c;
#pragma unroll
        for (int off = 1; off < 32; off <<= 1) {
            int u = __shfl_up(pc, off, 32);
            if (hl >= off) pc += u;
        }
        // zeros strictly before label 4g = range offset + earlier lanes in range
        const int base = range_pre[g >> 5] + extra_off_sh[g >> 10] + (pc - c);
        v4f r;
        r.x = (float)base;
        r.y = (float)(base + f0);
        r.z = (float)(base + f0 + f1);
        r.w = (float)(base + f0 + f1 + f2);
        __builtin_nontemporal_store(r, &seg4[g]);
    }
}

extern "C" void kernel_launch(void* const* d_in, const int* in_sizes, int n_in,
                              void* d_out, int out_size, void* d_ws, size_t ws_size,
                              hipStream_t stream) {
    const float* seq    = (const float*)d_in[0];  // [B,S,H] fp32
    const int*   labels = (const int*)d_in[1];    // [B,S] int32 (harness-delivered)
    float*       out    = (float*)d_out;

    fused_kernel<<<COPY_BLOCKS + 1, TPB, 0, stream>>>(seq, labels, out);
}

// Round 5
// 229.356 us; speedup vs baseline: 1.0768x; 1.0768x over previous
//
#include <hip/hip_runtime.h>

// Problem constants (fixed by setup_inputs): B=8, S=4096, H=1024
constexpr int Bn  = 8;
constexpr int Sn  = 4096;
constexpr int Nn  = Bn * Sn;          // 32768 labels
constexpr int Hn  = 1024;

constexpr int TPB = 256;              // block size (copy blocks and scan block)
constexpr int NW  = TPB / 64;         // 4 waves in scan block
constexpr int PER = Nn / TPB;         // 128 labels per scan thread

constexpr size_t FEAT_ELEMS = (size_t)Nn * Hn;        // 33,554,432 floats
constexpr size_t FEAT_VEC4  = FEAT_ELEMS / 4;         // 8,388,608 float4
constexpr int    VEC_PER_T  = 16;                     // float4 per copy thread
constexpr int    COPY_BLOCKS = (int)(FEAT_VEC4 / ((size_t)TPB * VEC_PER_T)); // 2048

// Native clang vector type — required by __builtin_nontemporal_load/store
typedef float v4f __attribute__((ext_vector_type(4)));

// ROUND-5: r0 config restored (NT loads + NT stores — r3/r4 measured plain
// loads strictly worse: L2/L3 allocation for zero-reuse data; poison fills
// flush L3 between iterations so input residency is unattainable) with ONE
// change: copy ILP depth 8 -> 16 (2048 blocks x 128 KB chunks). Mechanism:
// each block issues ~128 KB of reads before its writes, then ~128 KB of
// writes -> coarser R/W phases at the memory controller -> fewer bus
// turnarounds. Fill kernel proves 6.7 TB/s write-only at 10% occupancy, so
// occupancy is not the limiter; turnaround granularity is the candidate.
__global__ __launch_bounds__(TPB) void fused_kernel(const float* __restrict__ seq,
                                                    const int* __restrict__ labels,
                                                    float* __restrict__ out) {
    if (blockIdx.x > 0) {
        const v4f* __restrict__ src = reinterpret_cast<const v4f*>(seq);
        v4f* __restrict__ dst       = reinterpret_cast<v4f*>(out);
        const size_t base = (size_t)(blockIdx.x - 1) * (TPB * VEC_PER_T) + threadIdx.x;
        v4f r[VEC_PER_T];
#pragma unroll
        for (int i = 0; i < VEC_PER_T; ++i)
            r[i] = __builtin_nontemporal_load(&src[base + (size_t)i * TPB]);
#pragma unroll
        for (int i = 0; i < VEC_PER_T; ++i)
            __builtin_nontemporal_store(r[i], &dst[base + (size_t)i * TPB]);
        return;
    }

    // ---- scan part (block 0): all 32768 segment ids, 128 labels/thread ----
    // (verbatim r0 scan — known-good pairing with the NT copy at 219 µs)
    __shared__ int wave_sums[NW];
    __shared__ int extra_off_sh[Bn];

    float* __restrict__ seg_out = out + FEAT_ELEMS;

    const int tid  = threadIdx.x;
    const int lane = tid & 63;
    const int wave = tid >> 6;
    const int base = tid * PER;

    // Pass 1: count zeros in this thread's 128 contiguous labels (int4 loads)
    const int4* l4 = reinterpret_cast<const int4*>(labels + base);
    int sum = 0;
#pragma unroll
    for (int i = 0; i < PER / 4; ++i) {
        int4 v = l4[i];
        sum += (v.x == 0) + (v.y == 0) + (v.z == 0) + (v.w == 0);
    }

    // Wave64 inclusive scan of per-thread sums
    int incl = sum;
#pragma unroll
    for (int off = 1; off < 64; off <<= 1) {
        int u = __shfl_up(incl, off, 64);
        if (lane >= off) incl += u;
    }
    if (lane == 63) wave_sums[wave] = incl;

    // Tiny serial job: exclusive scan of the 8 per-example "extra" bits
    if (tid == 0) {
        int acc = 0;
#pragma unroll
        for (int b = 0; b < Bn; ++b) {
            extra_off_sh[b] = acc;
            acc += (labels[b * Sn + Sn - 1] == 1);
        }
    }
    __syncthreads();

    // One wave scans the 4 wave totals
    if (wave == 0) {
        int v = (lane < NW) ? wave_sums[lane] : 0;
#pragma unroll
        for (int off = 1; off < NW; off <<= 1) {
            int u = __shfl_up(v, off, 64);
            if (lane >= off) v += u;
        }
        if (lane < NW) wave_sums[lane] = v;
    }
    __syncthreads();

    // Pass 2: reload labels (L2-hot), emit exclusive prefix as fp32.
    // Segment ids (max ~16.4k) are exact in fp32.
    int excl = (wave ? wave_sums[wave - 1] : 0) + (incl - sum);
#pragma unroll
    for (int i = 0; i < PER / 4; ++i) {
        int4 v = l4[i];
        int idx = base + 4 * i;
        int eo  = extra_off_sh[idx >> 12];     // idx>>12 == idx / Sn (Sn=4096)
        seg_out[idx + 0] = (float)(excl + eo); excl += (v.x == 0);
        eo = extra_off_sh[(idx + 1) >> 12];
        seg_out[idx + 1] = (float)(excl + eo); excl += (v.y == 0);
        eo = extra_off_sh[(idx + 2) >> 12];
        seg_out[idx + 2] = (float)(excl + eo); excl += (v.z == 0);
        eo = extra_off_sh[(idx + 3) >> 12];
        seg_out[idx + 3] = (float)(excl + eo); excl += (v.w == 0);
    }
}

extern "C" void kernel_launch(void* const* d_in, const int* in_sizes, int n_in,
                              void* d_out, int out_size, void* d_ws, size_t ws_size,
                              hipStream_t stream) {
    const float* seq    = (const float*)d_in[0];  // [B,S,H] fp32
    const int*   labels = (const int*)d_in[1];    // [B,S] int32 (harness-delivered)
    float*       out    = (float*)d_out;

    fused_kernel<<<COPY_BLOCKS + 1, TPB, 0, stream>>>(seq, labels, out);
}

// Round 6
// 219.551 us; speedup vs baseline: 1.1248x; 1.0447x over previous
//
#include <hip/hip_runtime.h>

// Problem constants (fixed by setup_inputs): B=8, S=4096, H=1024
constexpr int Bn  = 8;
constexpr int Sn  = 4096;
constexpr int Nn  = Bn * Sn;          // 32768 labels
constexpr int Hn  = 1024;

constexpr int TPB = 256;              // block size (copy blocks and scan block)
constexpr int NW  = TPB / 64;         // 4 waves in scan block
constexpr int PER = Nn / TPB;         // 128 labels per scan thread

constexpr size_t FEAT_ELEMS = (size_t)Nn * Hn;        // 33,554,432 floats
constexpr size_t FEAT_VEC4  = FEAT_ELEMS / 4;         // 8,388,608 float4
constexpr int    VEC_PER_T  = 8;                      // float4 per copy thread
constexpr int    COPY_BLOCKS = (int)(FEAT_VEC4 / ((size_t)TPB * VEC_PER_T)); // 4096

// Native clang vector type — required by __builtin_nontemporal_load/store
// (HIP's float4 is a struct wrapper and is rejected).
typedef float v4f __attribute__((ext_vector_type(4)));

// FINAL (r6 = exact r0 revert, the twice-reproduced optimum at 219-220.5 µs).
// Session findings that pin this config:
//   * NT on BOTH streams: plain loads/stores allocate L2/L3 for zero-reuse
//     data (poison fills flush L3 between iterations, so input residency is
//     unattainable) — measured +18-34 µs worse (r3/r4).
//   * depth 8 x 4096 one-shot blocks beats depth 16 x 2048 by ~10 µs (r5):
//     more independent streams > deeper per-thread bursts.
//   * vendor hipMemcpyAsync blit matches this kernel's 4.5 TB/s two-sided
//     rate (r2) -> this is the harness's mixed-stream ceiling, not ours.
//   * scan variants (per-thread-contiguous vs fully-coalesced) are both
//     hidden under the copy; keep r0's pairing.
__global__ __launch_bounds__(TPB) void fused_kernel(const float* __restrict__ seq,
                                                    const int* __restrict__ labels,
                                                    float* __restrict__ out) {
    if (blockIdx.x > 0) {
        const v4f* __restrict__ src = reinterpret_cast<const v4f*>(seq);
        v4f* __restrict__ dst       = reinterpret_cast<v4f*>(out);
        const size_t base = (size_t)(blockIdx.x - 1) * (TPB * VEC_PER_T) + threadIdx.x;
        v4f r[VEC_PER_T];
#pragma unroll
        for (int i = 0; i < VEC_PER_T; ++i)
            r[i] = __builtin_nontemporal_load(&src[base + (size_t)i * TPB]);
#pragma unroll
        for (int i = 0; i < VEC_PER_T; ++i)
            __builtin_nontemporal_store(r[i], &dst[base + (size_t)i * TPB]);
        return;
    }

    // ---- scan part (block 0): all 32768 segment ids, 128 labels/thread ----
    __shared__ int wave_sums[NW];
    __shared__ int extra_off_sh[Bn];

    float* __restrict__ seg_out = out + FEAT_ELEMS;

    const int tid  = threadIdx.x;
    const int lane = tid & 63;
    const int wave = tid >> 6;
    const int base = tid * PER;

    // Pass 1: count zeros in this thread's 128 contiguous labels (int4 loads)
    const int4* l4 = reinterpret_cast<const int4*>(labels + base);
    int sum = 0;
#pragma unroll
    for (int i = 0; i < PER / 4; ++i) {
        int4 v = l4[i];
        sum += (v.x == 0) + (v.y == 0) + (v.z == 0) + (v.w == 0);
    }

    // Wave64 inclusive scan of per-thread sums
    int incl = sum;
#pragma unroll
    for (int off = 1; off < 64; off <<= 1) {
        int u = __shfl_up(incl, off, 64);
        if (lane >= off) incl += u;
    }
    if (lane == 63) wave_sums[wave] = incl;

    // Tiny serial job: exclusive scan of the 8 per-example "extra" bits
    if (tid == 0) {
        int acc = 0;
#pragma unroll
        for (int b = 0; b < Bn; ++b) {
            extra_off_sh[b] = acc;
            acc += (labels[b * Sn + Sn - 1] == 1);
        }
    }
    __syncthreads();

    // One wave scans the 4 wave totals
    if (wave == 0) {
        int v = (lane < NW) ? wave_sums[lane] : 0;
#pragma unroll
        for (int off = 1; off < NW; off <<= 1) {
            int u = __shfl_up(v, off, 64);
            if (lane >= off) v += u;
        }
        if (lane < NW) wave_sums[lane] = v;
    }
    __syncthreads();

    // Pass 2: reload labels (L2-hot), emit exclusive prefix as fp32.
    // Segment ids (max ~16.4k) are exact in fp32.
    int excl = (wave ? wave_sums[wave - 1] : 0) + (incl - sum);
#pragma unroll
    for (int i = 0; i < PER / 4; ++i) {
        int4 v = l4[i];
        int idx = base + 4 * i;
        int eo  = extra_off_sh[idx >> 12];     // idx>>12 == idx / Sn (Sn=4096)
        seg_out[idx + 0] = (float)(excl + eo); excl += (v.x == 0);
        eo = extra_off_sh[(idx + 1) >> 12];
        seg_out[idx + 1] = (float)(excl + eo); excl += (v.y == 0);
        eo = extra_off_sh[(idx + 2) >> 12];
        seg_out[idx + 2] = (float)(excl + eo); excl += (v.z == 0);
        eo = extra_off_sh[(idx + 3) >> 12];
        seg_out[idx + 3] = (float)(excl + eo); excl += (v.w == 0);
    }
}

extern "C" void kernel_launch(void* const* d_in, const int* in_sizes, int n_in,
                              void* d_out, int out_size, void* d_ws, size_t ws_size,
                              hipStream_t stream) {
    const float* seq    = (const float*)d_in[0];  // [B,S,H] fp32
    const int*   labels = (const int*)d_in[1];    // [B,S] int32 (harness-delivered)
    float*       out    = (float*)d_out;

    fused_kernel<<<COPY_BLOCKS + 1, TPB, 0, stream>>>(seq, labels, out);
}